// Round 1
// baseline (357.366 us; speedup 1.0000x reference)
//
#include <hip/hip_runtime.h>
#include <math.h>

// Problem constants
#define T_  204
#define I_  5
#define H_  24
#define L_  10
#define O_  612
#define Bsz 8192

typedef _Float16 half8 __attribute__((ext_vector_type(8)));
typedef _Float16 half2t __attribute__((ext_vector_type(2)));
typedef float    float4t __attribute__((ext_vector_type(4)));

union U16B { float4t f4; half8 h8; float f[4]; _Float16 h[8]; half2t h2[4]; };

__device__ __forceinline__ float fast_rcp(float x){ return __builtin_amdgcn_rcpf(x); }
__device__ __forceinline__ float fast_ex2(float x){ return __builtin_amdgcn_exp2f(x); }
__device__ __forceinline__ half2t pk2(float a, float b){
    return __builtin_bit_cast(half2t, __builtin_amdgcn_cvt_pkrtz(a, b));
}

#define MFMA16(a,b,c) __builtin_amdgcn_mfma_f32_16x16x32_f16((a),(b),(c),0,0,0)

#define L2E  1.44269504f
#define L2E2 2.88539008f

__device__ __forceinline__ float sigm2(float x){ return fast_rcp(1.f + fast_ex2(x * -L2E)); }
__device__ __forceinline__ float tanh2(float x){ return 2.f * fast_rcp(1.f + fast_ex2(x * -L2E2)) - 1.f; }

// Unit owned by lane-quad q, tile T (q<3: 8q+T; q==3: overflow units 6,7,14,15,22,23)
__device__ __forceinline__ int unit_of(int q, int T) {
    return (q < 3) ? (8*q + T) : (8*(T >> 1) + 6 + (T & 1));
}

// Prepack fc0_w into per-timestep fp16 A-fragments (A[m=l][k=j], zeros elsewhere).
__global__ __launch_bounds__(64)
void pack_fc0(const float* __restrict__ fc0_w, float4t* __restrict__ dst)
{
    const int t = blockIdx.x, lane = threadIdx.x;
    const int m = lane & 15, q = lane >> 4;
    U16B v;
    #pragma unroll
    for (int i = 0; i < 8; ++i) {
        const int k = 8*q + i;
        float f = (m < L_ && k < H_) ? fc0_w[m*(T_*H_) + t*H_ + k] : 0.0f;
        v.h[i] = (_Float16)f;
    }
    dst[t*64 + lane] = v.f4;
}

#define BCH(x) __builtin_bit_cast(half2t, (x))

// R12: one dependent LSTM chain per wave leaves ~1100cy/step of uncovered stall
// (MfmaUtil 3.2%, VALUBusy 29%, 1 wave/SIMD => nothing fills stalls). Two
// independent 16-batch tiles per wave give intra-wave ILP: chain A's stalls are
// filled by chain B's issue. Also: the old xC=xN / fa=fan copies forced the
// vmcnt wait into the SAME iteration the load was issued (shadow ~500cy < HBM
// ~900cy). Unroll-by-2 with ping-pong buffers (xE/xO, fa0/fa1), loads issued at
// the step bottom AFTER consumption -> true 2-step (~1400cy) copy-free shadow.
#define LSTM_STEP(tcur, xCA, xCB, facur)                                        \
  {                                                                             \
    float4t DA0 = MFMA16(Ag[0], BA.h8, zf4);                                    \
    float4t DB0 = MFMA16(Ag[0], BB.h8, zf4);                                    \
    float4t DA1 = MFMA16(Ag[1], BA.h8, zf4);                                    \
    float4t DB1 = MFMA16(Ag[1], BB.h8, zf4);                                    \
    float4t DA2 = MFMA16(Ag[2], BA.h8, zf4);                                    \
    float4t DB2 = MFMA16(Ag[2], BB.h8, zf4);                                    \
    float4t DA3 = MFMA16(Ag[3], BA.h8, zf4);                                    \
    float4t DB3 = MFMA16(Ag[3], BB.h8, zf4);                                    \
    float4t DA4 = MFMA16(Ag[4], BA.h8, zf4);                                    \
    float4t DB4 = MFMA16(Ag[4], BB.h8, zf4);                                    \
    float4t DA5 = MFMA16(Ag[5], BA.h8, zf4);                                    \
    float4t DB5 = MFMA16(Ag[5], BB.h8, zf4);                                    \
    float4t DAv[6] = {DA0, DA1, DA2, DA3, DA4, DA5};                            \
    float4t DBv[6] = {DB0, DB1, DB2, DB3, DB4, DB5};                            \
    float hA[6];                                                                \
    float hB[6];                                                                \
    _Pragma("unroll")                                                           \
    for (int T6 = 0; T6 < 6; ++T6) {                                            \
      const float siA = sigm2(DAv[T6][0]);                                      \
      const float siB = sigm2(DBv[T6][0]);                                      \
      const float sfA = sigm2(DAv[T6][1]);                                      \
      const float sfB = sigm2(DBv[T6][1]);                                      \
      const float tgA = tanh2(DAv[T6][2]);                                      \
      const float tgB = tanh2(DBv[T6][2]);                                      \
      const float soA = sigm2(DAv[T6][3]);                                      \
      const float soB = sigm2(DBv[T6][3]);                                      \
      cA[T6] = fmaf(sfA, cA[T6], siA * tgA);                                    \
      cB[T6] = fmaf(sfB, cB[T6], siB * tgB);                                    \
      hA[T6] = soA * tanh2(cA[T6]);                                             \
      hB[T6] = soB * tanh2(cB[T6]);                                             \
    }                                                                           \
    const float PA0 = __builtin_bit_cast(float, pk2(hA[0], hA[1]));             \
    const float PA1 = __builtin_bit_cast(float, pk2(hA[2], hA[3]));             \
    const float PA2 = __builtin_bit_cast(float, pk2(hA[4], hA[5]));             \
    const float PB0 = __builtin_bit_cast(float, pk2(hB[0], hB[1]));             \
    const float PB1 = __builtin_bit_cast(float, pk2(hB[2], hB[3]));             \
    const float PB2 = __builtin_bit_cast(float, pk2(hB[4], hB[5]));             \
    const int srcl = 48 + m;                                                    \
    const float rA0 = __shfl(PA0, srcl, 64);                                    \
    const float rA1 = __shfl(PA1, srcl, 64);                                    \
    const float rA2 = __shfl(PA2, srcl, 64);                                    \
    const float rB0 = __shfl(PB0, srcl, 64);                                    \
    const float rB1 = __shfl(PB1, srcl, 64);                                    \
    const float rB2 = __shfl(PB2, srcl, 64);                                    \
    const float rcvA = (q == 0) ? rA0 : ((q == 1) ? rA1 : rA2);                 \
    const float rcvB = (q == 0) ? rB0 : ((q == 1) ? rB1 : rB2);                 \
    if (q < 3) {                                                                \
      BA.h2[0] = BCH(PA0); BA.h2[1] = BCH(PA1);                                 \
      BA.h2[2] = BCH(PA2); BA.h2[3] = BCH(rcvA);                                \
      BB.h2[0] = BCH(PB0); BB.h2[1] = BCH(PB1);                                 \
      BB.h2[2] = BCH(PB2); BB.h2[3] = BCH(rcvB);                                \
    } else {                                                                    \
      BA.h2[0] = pk2(xCA[0], xCA[1]);                                           \
      BA.h2[1] = pk2(xCA[2], xCA[3]);                                           \
      BA.h2[2] = pk2(xCA[4], 1.0f);                                             \
      BA.h2[3] = pk2(0.f, 0.f);                                                 \
      BB.h2[0] = pk2(xCB[0], xCB[1]);                                           \
      BB.h2[1] = pk2(xCB[2], xCB[3]);                                           \
      BB.h2[2] = pk2(xCB[4], 1.0f);                                             \
      BB.h2[3] = pk2(0.f, 0.f);                                                 \
    }                                                                           \
    U16B fF; fF.f4 = facur;                                                     \
    accFA = MFMA16(fF.h8, BA.h8, accFA);                                        \
    accFB = MFMA16(fF.h8, BB.h8, accFB);                                        \
    {                                                                           \
      const int tpx = ((tcur) + 3 < T_) ? (tcur) + 3 : (T_ - 1);                \
      if (q == 3) {                                                             \
        _Pragma("unroll")                                                       \
        for (int i = 0; i < I_; ++i) {                                          \
          xCA[i] = xpA[tpx * I_ + i];                                           \
          xCB[i] = xpB[tpx * I_ + i];                                           \
        }                                                                       \
      }                                                                         \
      const int tfx = ((tcur) + 2 < T_) ? (tcur) + 2 : (T_ - 1);                \
      facur = fc0A[tfx * 64 + lane];                                            \
    }                                                                           \
  }

__global__ __launch_bounds__(64, 1)
void lstm_mfma(const float* __restrict__ x,
               const float* __restrict__ W_ih,
               const float* __restrict__ W_hh,
               const float* __restrict__ b_ih,
               const float* __restrict__ b_hh,
               const float* __restrict__ fc0_b,
               const float* __restrict__ out_w,
               const float* __restrict__ out_b,
               const float4t* __restrict__ fc0A,   // prepacked in d_ws
               float* __restrict__ out)
{
    __shared__ __align__(16) _Float16 actL[32*24];  // epilogue staging only

    const int lane = threadIdx.x;
    const int m = lane & 15;        // element col / A row-within-tile
    const int q = lane >> 4;        // quad
    const int elemA = blockIdx.x * 32 + m;     // tile A batch element
    const int elemB = elemA + 16;              // tile B batch element

    const float4t zf4 = {0.f, 0.f, 0.f, 0.f};

    // ---- gate A-fragments (shared by both tiles) ----
    half8 Ag[6];
    #pragma unroll
    for (int T6 = 0; T6 < 6; ++T6) {
        const int u = unit_of(m >> 2, T6);
        const int srow = (m & 3) * H_ + u;       // torch gate-major row
        float wv[8];
        if (q < 3) {
            const float4t* pw = (const float4t*)(W_hh + srow*H_ + 8*q);
            float4t wa = pw[0], wb = pw[1];
            #pragma unroll
            for (int i = 0; i < 4; ++i) { wv[i] = wa[i]; wv[4+i] = wb[i]; }
        } else {
            #pragma unroll
            for (int i = 0; i < 8; ++i) wv[i] = 0.f;
            #pragma unroll
            for (int i = 0; i < I_; ++i) wv[i] = W_ih[srow*I_ + i];
            wv[5] = b_ih[srow] + b_hh[srow];
        }
        U16B tw;
        #pragma unroll
        for (int i = 0; i < 8; ++i) tw.h[i] = (_Float16)wv[i];
        Ag[T6] = tw.h8;
    }

    const float* xpA = x + (size_t)elemA * (T_*I_);
    const float* xpB = x + (size_t)elemB * (T_*I_);

    // ---- initial B-frags [h=0 | x_0 | 1 | 0,0] ----
    U16B BA, BB;
    if (q == 3) {
        BA.h2[0] = pk2(xpA[0], xpA[1]);
        BA.h2[1] = pk2(xpA[2], xpA[3]);
        BA.h2[2] = pk2(xpA[4], 1.0f);
        BA.h2[3] = pk2(0.f, 0.f);
        BB.h2[0] = pk2(xpB[0], xpB[1]);
        BB.h2[1] = pk2(xpB[2], xpB[3]);
        BB.h2[2] = pk2(xpB[4], 1.0f);
        BB.h2[3] = pk2(0.f, 0.f);
    } else {
        BA.f4 = zf4;
        BB.f4 = zf4;
    }

    // ping-pong x prefetch buffers: xE consumed at even t (holds x(t+1)),
    // xO at odd t; reloaded at step bottom after consumption (2-step shadow).
    float xEA[I_] = {0,0,0,0,0}, xOA[I_] = {0,0,0,0,0};
    float xEB[I_] = {0,0,0,0,0}, xOB[I_] = {0,0,0,0,0};
    if (q == 3) {
        #pragma unroll
        for (int i = 0; i < I_; ++i) {
            xEA[i] = xpA[1*I_ + i];
            xOA[i] = xpA[2*I_ + i];
            xEB[i] = xpB[1*I_ + i];
            xOB[i] = xpB[2*I_ + i];
        }
    }

    float cA[6] = {0,0,0,0,0,0};
    float cB[6] = {0,0,0,0,0,0};
    float4t accFA = zf4, accFB = zf4;
    float4t fa0 = fc0A[lane];          // fc0 frag for even t (starts t=0)
    float4t fa1 = fc0A[64 + lane];     // fc0 frag for odd t (starts t=1)

    // ================= time loop (no barriers, no LDS) =================
    for (int t = 0; t < T_; t += 2) {
        LSTM_STEP(t,     xEA, xEB, fa0)
        LSTM_STEP(t + 1, xOA, xOB, fa1)
    }

    // ================= epilogue (dual-tile variant of validated R7/R8) =====
    float avA[4], avB[4];
    #pragma unroll
    for (int r = 0; r < 4; ++r) {
        const int l = 4*q + r;
        const float fb = (l < L_) ? fc0_b[l] : 0.f;
        const float vA = accFA[r] + fb;
        const float vB = accFB[r] + fb;
        avA[r] = (l < L_) ? fmaxf(vA, 0.f) : 0.f;
        avB[r] = (l < L_) ? fmaxf(vB, 0.f) : 0.f;
    }
    *(half2t*)(&actL[m*24 + 4*q])          = pk2(avA[0], avA[1]);
    *(half2t*)(&actL[m*24 + 4*q + 2])      = pk2(avA[2], avA[3]);
    *(half2t*)(&actL[(16+m)*24 + 4*q])     = pk2(avB[0], avB[1]);
    *(half2t*)(&actL[(16+m)*24 + 4*q + 2]) = pk2(avB[2], avB[3]);
    __builtin_amdgcn_wave_barrier();

    U16B BaA, BaB;
    if (q < 2) {
        BaA.f4 = *(const float4t*)(&actL[m*24 + q*8]);
        BaB.f4 = *(const float4t*)(&actL[(16+m)*24 + q*8]);
    } else {
        BaA.f4 = zf4;            // k>=16 unused (out_w A-frag zero there)
        BaB.f4 = zf4;
    }

    for (int Tt = 0; Tt < 39; ++Tt) {
        const int row = 16*Tt + m;
        float w0=0.f,w1=0.f,w2=0.f,w3=0.f,w4=0.f,w5=0.f,w6=0.f,w7=0.f;
        if (row < O_ && q < 2) {
            const float2* p2 = (const float2*)(out_w + row*L_);
            if (q == 0) {
                float2 a = p2[0], b = p2[1], cc = p2[2], dd = p2[3];
                w0=a.x; w1=a.y; w2=b.x; w3=b.y; w4=cc.x; w5=cc.y; w6=dd.x; w7=dd.y;
            } else {
                float2 a = p2[4];
                w0=a.x; w1=a.y;
            }
        }
        U16B Aw;
        Aw.h2[0] = pk2(w0,w1); Aw.h2[1] = pk2(w2,w3);
        Aw.h2[2] = pk2(w4,w5); Aw.h2[3] = pk2(w6,w7);

        float4t dA = MFMA16(Aw.h8, BaA.h8, zf4);
        float4t dB = MFMA16(Aw.h8, BaB.h8, zf4);

        const int ob = 16*Tt + 4*q;
        if (ob < O_) {
            const float4t bias = *(const float4t*)(out_b + ob);
            #pragma unroll
            for (int r = 0; r < 4; ++r) { dA[r] += bias[r]; dB[r] += bias[r]; }
            *(float4t*)(out + (size_t)elemA*O_ + ob) = dA;
            *(float4t*)(out + (size_t)elemB*O_ + ob) = dB;
        }
    }
}

extern "C" void kernel_launch(void* const* d_in, const int* in_sizes, int n_in,
                              void* d_out, int out_size, void* d_ws, size_t ws_size,
                              hipStream_t stream)
{
    const float* x     = (const float*)d_in[0];
    const float* W_ih  = (const float*)d_in[1];
    const float* W_hh  = (const float*)d_in[2];
    const float* b_ih  = (const float*)d_in[3];
    const float* b_hh  = (const float*)d_in[4];
    const float* fc0_w = (const float*)d_in[5];
    const float* fc0_b = (const float*)d_in[6];
    const float* out_w = (const float*)d_in[7];
    const float* out_b = (const float*)d_in[8];
    float* out = (float*)d_out;
    (void)ws_size;

    pack_fc0<<<dim3(T_), dim3(64), 0, stream>>>(fc0_w, (float4t*)d_ws);
    lstm_mfma<<<dim3(Bsz/32), dim3(64), 0, stream>>>(
        x, W_ih, W_hh, b_ih, b_hh, fc0_b, out_w, out_b,
        (const float4t*)d_ws, out);
}

// Round 2
// 218.787 us; speedup vs baseline: 1.6334x; 1.6334x over previous
//
#include <hip/hip_runtime.h>
#include <math.h>

// Problem constants
#define T_  204
#define I_  5
#define H_  24
#define L_  10
#define O_  612
#define Bsz 8192

typedef _Float16 half8 __attribute__((ext_vector_type(8)));
typedef _Float16 half2t __attribute__((ext_vector_type(2)));
typedef float    float4t __attribute__((ext_vector_type(4)));

union U16B { float4t f4; half8 h8; float f[4]; _Float16 h[8]; half2t h2[4]; };

__device__ __forceinline__ float fast_rcp(float x){ return __builtin_amdgcn_rcpf(x); }
__device__ __forceinline__ float fast_ex2(float x){ return __builtin_amdgcn_exp2f(x); }
__device__ __forceinline__ half2t pk2(float a, float b){
    return __builtin_bit_cast(half2t, __builtin_amdgcn_cvt_pkrtz(a, b));
}

#define MFMA16(a,b,c) __builtin_amdgcn_mfma_f32_16x16x32_f16((a),(b),(c),0,0,0)

#define L2E  1.44269504f
#define L2E2 2.88539008f

__device__ __forceinline__ float sigm2(float x){ return fast_rcp(1.f + fast_ex2(x * -L2E)); }
__device__ __forceinline__ float tanh2(float x){ return 2.f * fast_rcp(1.f + fast_ex2(x * -L2E2)) - 1.f; }

// Unit owned by lane-quad q, tile T (q<3: 8q+T; q==3: overflow units 6,7,14,15,22,23)
__device__ __forceinline__ int unit_of(int q, int T) {
    return (q < 3) ? (8*q + T) : (8*(T >> 1) + 6 + (T & 1));
}

// Prepack fc0_w into per-timestep fp16 A-fragments (A[m=l][k=j], zeros elsewhere).
__global__ __launch_bounds__(64)
void pack_fc0(const float* __restrict__ fc0_w, float4t* __restrict__ dst)
{
    const int t = blockIdx.x, lane = threadIdx.x;
    const int m = lane & 15, q = lane >> 4;
    U16B v;
    #pragma unroll
    for (int i = 0; i < 8; ++i) {
        const int k = 8*q + i;
        float f = (m < L_ && k < H_) ? fc0_w[m*(T_*H_) + t*H_ + k] : 0.0f;
        v.h[i] = (_Float16)f;
    }
    dst[t*64 + lane] = v.f4;
}

// R13: R12 showed wall-time scales with per-wave instruction count (dual-tile
// doubled time exactly; VALU cycles conserved) -> issue-bound per wave, and
// only 512 of 1024 SIMDs were active. Split the 24 units across 2 waves/WG
// (1024 waves = 1/SIMD): each wave runs 3 gate MFMAs + 3 units' activations
// (15 trans vs 30), exchanges h halves via 1.5KB double-buffered LDS with raw
// s_barrier + lgkmcnt(0)-only wait (vmem prefetches stay in flight across the
// barrier). The 6 ds_bpermutes die; B rebuild = one ds_read_b128. fc0 acc on
// wave 1; epilogue out-tiles split by parity. f16 rounding identical (pkrtz).
#define LSTM_STEP(tcur, xC, facur)                                              \
  {                                                                             \
    float4t D0 = MFMA16(Ag[0], B.h8, zf4);                                      \
    float4t D1 = MFMA16(Ag[1], B.h8, zf4);                                      \
    float4t D2 = MFMA16(Ag[2], B.h8, zf4);                                      \
    float hh0, hh1, hh2;                                                        \
    {                                                                           \
      const float si0 = sigm2(D0[0]), sf0 = sigm2(D0[1]);                       \
      const float tg0 = tanh2(D0[2]), so0 = sigm2(D0[3]);                       \
      cc0 = fmaf(sf0, cc0, si0 * tg0);  hh0 = so0 * tanh2(cc0);                 \
      const float si1 = sigm2(D1[0]), sf1 = sigm2(D1[1]);                       \
      const float tg1 = tanh2(D1[2]), so1 = sigm2(D1[3]);                       \
      cc1 = fmaf(sf1, cc1, si1 * tg1);  hh1 = so1 * tanh2(cc1);                 \
      const float si2 = sigm2(D2[0]), sf2 = sigm2(D2[1]);                       \
      const float tg2 = tanh2(D2[2]), so2 = sigm2(D2[3]);                       \
      cc2 = fmaf(sf2, cc2, si2 * tg2);  hh2 = so2 * tanh2(cc2);                 \
    }                                                                           \
    const int bofs = ((tcur) & 1) * 384;                                        \
    const half2t pr = (wv == 0) ? pk2(hh0, hh1) : pk2(hh1, hh2);                \
    const float  sg = (wv == 0) ? hh2 : hh0;                                    \
    const half2t sgp = pk2(sg, sg);                                             \
    *(half2t*)(&hbuf[bofs + pairElem]) = pr;                                    \
    hbuf[bofs + snglElem] = sgp[0];                                             \
    asm volatile("s_waitcnt lgkmcnt(0)" ::: "memory");                          \
    __builtin_amdgcn_s_barrier();                                               \
    asm volatile("" ::: "memory");                                              \
    if (q < 3) {                                                                \
      B.f4 = *(const float4t*)(&hbuf[bofs + m*24 + 8*q]);                       \
    } else {                                                                    \
      B.h2[0] = pk2(xC[0], xC[1]);                                              \
      B.h2[1] = pk2(xC[2], xC[3]);                                              \
      B.h2[2] = pk2(xC[4], 1.0f);                                               \
      B.h2[3] = pk2(0.f, 0.f);                                                  \
    }                                                                           \
    if (wv == 1) {                                                              \
      U16B fF; fF.f4 = facur;                                                   \
      accF = MFMA16(fF.h8, B.h8, accF);                                         \
      const int tfx = ((tcur) + 2 < T_) ? (tcur) + 2 : (T_ - 1);                \
      facur = fc0A[tfx * 64 + lane64];                                          \
    }                                                                           \
    if (q == 3) {                                                               \
      const int tpx = ((tcur) + 3 < T_) ? (tcur) + 3 : (T_ - 1);                \
      _Pragma("unroll")                                                         \
      for (int i = 0; i < I_; ++i) xC[i] = xp[tpx * I_ + i];                    \
    }                                                                           \
  }

__global__ __launch_bounds__(128)
void lstm_mfma(const float* __restrict__ x,
               const float* __restrict__ W_ih,
               const float* __restrict__ W_hh,
               const float* __restrict__ b_ih,
               const float* __restrict__ b_hh,
               const float* __restrict__ fc0_b,
               const float* __restrict__ out_w,
               const float* __restrict__ out_b,
               const float4t* __restrict__ fc0A,   // prepacked in d_ws
               float* __restrict__ out)
{
    // double-buffered h exchange (2 x 16 batch x 24 units, f16) + epilogue staging
    __shared__ __align__(16) _Float16 hbuf[2*16*24];

    const int tid  = threadIdx.x;
    const int lane64 = tid & 63;
    const int m = tid & 15;             // batch col / A row-within-tile
    const int q = (tid >> 4) & 3;       // quad within wave
    const int wv = tid >> 6;            // wave index (0: tiles 0-2, 1: tiles 3-5)
    const int elem = blockIdx.x * 16 + m;

    const float4t zf4 = {0.f, 0.f, 0.f, 0.f};

    // ---- gate A-fragments: this wave's 3 tiles ----
    half8 Ag[3];
    #pragma unroll
    for (int Tl = 0; Tl < 3; ++Tl) {
        const int T = 3*wv + Tl;
        const int u = unit_of(m >> 2, T);
        const int srow = (m & 3) * H_ + u;       // torch gate-major row
        float wval[8];
        if (q < 3) {
            const float4t* pw = (const float4t*)(W_hh + srow*H_ + 8*q);
            float4t wa = pw[0], wb = pw[1];
            #pragma unroll
            for (int i = 0; i < 4; ++i) { wval[i] = wa[i]; wval[4+i] = wb[i]; }
        } else {
            #pragma unroll
            for (int i = 0; i < 8; ++i) wval[i] = 0.f;
            #pragma unroll
            for (int i = 0; i < I_; ++i) wval[i] = W_ih[srow*I_ + i];
            wval[5] = b_ih[srow] + b_hh[srow];
        }
        U16B tw;
        #pragma unroll
        for (int i = 0; i < 8; ++i) tw.h[i] = (_Float16)wval[i];
        Ag[Tl] = tw.h8;
    }

    // ---- per-lane LDS write offsets for owned h units ----
    // wave0 lane(m,q): pair (u,u+1) at unit_of(q,0), single at unit_of(q,2)
    // wave1 lane(m,q): single at unit_of(q,3), pair (u,u+1) at unit_of(q,4)
    const int u_pair = (wv == 0) ? ((q < 3) ? 8*q     : 6 )
                                 : ((q < 3) ? 8*q + 4 : 22);
    const int u_sngl = (wv == 0) ? ((q < 3) ? 8*q + 2 : 14)
                                 : ((q < 3) ? 8*q + 3 : 15);
    const int pairElem = m*24 + u_pair;   // even -> 4B-aligned half2 store
    const int snglElem = m*24 + u_sngl;

    const float* xp = x + (size_t)elem * (T_*I_);

    // ---- initial B-frag [h=0 | x_0 | 1 | 0,0] ----
    U16B B;
    if (q == 3) {
        B.h2[0] = pk2(xp[0], xp[1]);
        B.h2[1] = pk2(xp[2], xp[3]);
        B.h2[2] = pk2(xp[4], 1.0f);
        B.h2[3] = pk2(0.f, 0.f);
    } else {
        B.f4 = zf4;
    }

    // ping-pong x prefetch (xE consumed at even t = x(t+1); xO at odd t),
    // reloaded at step bottom after consumption -> ~2-step vmem shadow.
    float xE[I_] = {0,0,0,0,0}, xO[I_] = {0,0,0,0,0};
    if (q == 3) {
        #pragma unroll
        for (int i = 0; i < I_; ++i) {
            xE[i] = xp[1*I_ + i];
            xO[i] = xp[2*I_ + i];
        }
    }

    float cc0 = 0.f, cc1 = 0.f, cc2 = 0.f;
    float4t accF = zf4;
    float4t fa0 = zf4, fa1 = zf4;
    if (wv == 1) {
        fa0 = fc0A[lane64];           // frag for even t (starts t=0)
        fa1 = fc0A[64 + lane64];      // frag for odd t  (starts t=1)
    }

    // ================= time loop =================
    #pragma unroll 1
    for (int t = 0; t < T_; t += 2) {
        LSTM_STEP(t,     xE, fa0)
        LSTM_STEP(t + 1, xO, fa1)
    }

    // ================= epilogue =================
    if (wv == 1) {
        float av[4];
        #pragma unroll
        for (int r = 0; r < 4; ++r) {
            const int l = 4*q + r;
            const float fb = (l < L_) ? fc0_b[l] : 0.f;
            const float v = accF[r] + fb;
            av[r] = (l < L_) ? fmaxf(v, 0.f) : 0.f;
        }
        *(half2t*)(&hbuf[m*24 + 4*q])     = pk2(av[0], av[1]);
        *(half2t*)(&hbuf[m*24 + 4*q + 2]) = pk2(av[2], av[3]);
    }
    asm volatile("s_waitcnt lgkmcnt(0)" ::: "memory");
    __builtin_amdgcn_s_barrier();
    asm volatile("" ::: "memory");

    U16B Ba;
    if (q < 2) Ba.f4 = *(const float4t*)(&hbuf[m*24 + q*8]);
    else       Ba.f4 = zf4;            // k>=16 unused (out_w A-frag zero there)

    for (int Tt = wv; Tt < 39; Tt += 2) {
        const int row = 16*Tt + m;
        float w0=0.f,w1=0.f,w2=0.f,w3=0.f,w4=0.f,w5=0.f,w6=0.f,w7=0.f;
        if (row < O_ && q < 2) {
            const float2* p2 = (const float2*)(out_w + row*L_);
            if (q == 0) {
                float2 a = p2[0], b = p2[1], cc = p2[2], dd = p2[3];
                w0=a.x; w1=a.y; w2=b.x; w3=b.y; w4=cc.x; w5=cc.y; w6=dd.x; w7=dd.y;
            } else {
                float2 a = p2[4];
                w0=a.x; w1=a.y;
            }
        }
        U16B Aw;
        Aw.h2[0] = pk2(w0,w1); Aw.h2[1] = pk2(w2,w3);
        Aw.h2[2] = pk2(w4,w5); Aw.h2[3] = pk2(w6,w7);

        float4t dd = MFMA16(Aw.h8, Ba.h8, zf4);

        const int ob = 16*Tt + 4*q;
        if (ob < O_) {
            const float4t bias = *(const float4t*)(out_b + ob);
            #pragma unroll
            for (int r = 0; r < 4; ++r) dd[r] += bias[r];
            *(float4t*)(out + (size_t)elem*O_ + ob) = dd;
        }
    }
}

extern "C" void kernel_launch(void* const* d_in, const int* in_sizes, int n_in,
                              void* d_out, int out_size, void* d_ws, size_t ws_size,
                              hipStream_t stream)
{
    const float* x     = (const float*)d_in[0];
    const float* W_ih  = (const float*)d_in[1];
    const float* W_hh  = (const float*)d_in[2];
    const float* b_ih  = (const float*)d_in[3];
    const float* b_hh  = (const float*)d_in[4];
    const float* fc0_w = (const float*)d_in[5];
    const float* fc0_b = (const float*)d_in[6];
    const float* out_w = (const float*)d_in[7];
    const float* out_b = (const float*)d_in[8];
    float* out = (float*)d_out;
    (void)ws_size;

    pack_fc0<<<dim3(T_), dim3(64), 0, stream>>>(fc0_w, (float4t*)d_ws);
    lstm_mfma<<<dim3(Bsz/16), dim3(128), 0, stream>>>(
        x, W_ih, W_hh, b_ih, b_hh, fc0_b, out_w, out_b,
        (const float4t*)d_ws, out);
}